// Round 6
// baseline (4507.830 us; speedup 1.0000x reference)
//
#include <hip/hip_runtime.h>
#include <hip/hip_bf16.h>
#include <math.h>

#define B_   2
#define S_   2048
#define H_   16
#define DH_  64
#define DM_  1024
#define PV_  512

typedef __attribute__((ext_vector_type(8))) short bf16x8;
typedef __attribute__((ext_vector_type(4))) float f32x4;

__device__ __forceinline__ float b2f(unsigned short u) {
  union { unsigned int i; float f; } v; v.i = ((unsigned int)u) << 16; return v.f;
}
__device__ __forceinline__ unsigned short f2b(float f) {
  union { float f; unsigned int i; } v; v.f = f;
  return (unsigned short)((v.i + 0x7fffu + ((v.i >> 16) & 1u)) >> 16);  // RNE
}
__device__ __forceinline__ f32x4 mfma16(bf16x8 a, bf16x8 b, f32x4 c) {
  return __builtin_amdgcn_mfma_f32_16x16x32_bf16(a, b, c, 0, 0, 0);
}

// ---------------- dtype probe: mode=1 if x looks like bf16, 0 if f32 ------------
// f32 data read as u16: even indices are mantissa halves -> uniform exponents
// (~25% in window). bf16 data: even indices are real bf16 of N(0,1) (~100%).
__global__ void k_probe(const unsigned short* __restrict__ x, int* __restrict__ mode) {
  __shared__ int cnt;
  if (threadIdx.x == 0) cnt = 0;
  __syncthreads();
  int local = 0;
  for (int i = threadIdx.x; i < 4096; i += 256) {
    unsigned short u = x[2 * i];
    int e = (u >> 7) & 0xFF;
    if (e >= 96 && e <= 160) local++;
  }
  atomicAdd(&cnt, local);
  __syncthreads();
  if (threadIdx.x == 0) mode[0] = (cnt > 2560) ? 1 : 0;   // >62.5% plausible -> bf16
}

// ---------------- RoPE sin/cos table: tab[s][i] = {sin, cos} (float2), i in [0,32)
__global__ void k_ropetab(float* tab) {
  int idx = blockIdx.x * 256 + threadIdx.x;       // s*32 + i
  if (idx >= S_ * 32) return;
  int s = idx >> 5, i = idx & 31;
  double inv = exp(-((double)(2 * i) / 64.0) * log(10000.0));
  double f = (double)s * inv;
  tab[idx * 2 + 0] = (float)sin(f);
  tab[idx * 2 + 1] = (float)cos(f);
}

// ---------------- GEMM: C = A[M][K] * W[K][N] + bias, runtime dtypes -------------
// aSel/oSel: 0=f32, 1=bf16(u16), 2=follow *mode. W/bias always follow *mode.
// arow0/crow0: row offsets (batch) applied inside, since element size varies.
__global__ __launch_bounds__(256) void k_gemmW(const void* __restrict__ Av,
                                               const void* __restrict__ Wv,
                                               const void* __restrict__ biasv,
                                               void* __restrict__ Cv,
                                               int M, int N, int K,
                                               const int* __restrict__ mode,
                                               int aSel, int oSel,
                                               int arow0, int crow0) {
  int md = mode[0];
  bool abf = (aSel == 2) ? (md != 0) : (aSel != 0);
  bool wbf = (md != 0);
  bool obf = (oSel == 2) ? (md != 0) : (oSel != 0);

  __shared__ unsigned short Alds[128][40];   // pad 32->40
  __shared__ unsigned short Blds[128][40];   // Blds[n][k] (transposed W tile)
  int lane = threadIdx.x & 63, w = threadIdx.x >> 6;
  int wr = w >> 1, wc = w & 1;
  int l16 = lane & 15, lq = lane >> 4;
  int m0 = blockIdx.y * 128, n0 = blockIdx.x * 128;
  f32x4 acc[4][4];
  #pragma unroll
  for (int a = 0; a < 4; ++a)
    #pragma unroll
    for (int b = 0; b < 4; ++b) acc[a][b] = (f32x4){0.f, 0.f, 0.f, 0.f};

  for (int k0 = 0; k0 < K; k0 += 32) {
    __syncthreads();
    // A: 128 rows x 32 k
    #pragma unroll
    for (int i = 0; i < 2; ++i) {
      int c = threadIdx.x + i * 256;
      int r = c >> 2, ch = (c & 3) * 8;
      size_t base = (size_t)(arow0 + m0 + r) * K + k0 + ch;
      if (abf) {
        *(uint4*)&Alds[r][ch] = *(const uint4*)((const unsigned short*)Av + base);
      } else {
        const float* A = (const float*)Av;
        float4 f0 = *(const float4*)(A + base);
        float4 f1 = *(const float4*)(A + base + 4);
        unsigned short* dst = &Alds[r][ch];
        dst[0] = f2b(f0.x); dst[1] = f2b(f0.y); dst[2] = f2b(f0.z); dst[3] = f2b(f0.w);
        dst[4] = f2b(f1.x); dst[5] = f2b(f1.y); dst[6] = f2b(f1.z); dst[7] = f2b(f1.w);
      }
    }
    // W: 32 k-rows x 128 n, coalesced read, transposed LDS write
    #pragma unroll
    for (int i = 0; i < 2; ++i) {
      int c = threadIdx.x + i * 256;                 // 0..511
      int kk = c >> 4, n8 = (c & 15) * 8;
      size_t base = (size_t)(k0 + kk) * N + n0 + n8;
      if (wbf) {
        union { uint4 u; unsigned short x[8]; } wv;
        wv.u = *(const uint4*)((const unsigned short*)Wv + base);
        #pragma unroll
        for (int e = 0; e < 8; ++e) Blds[n8 + e][kk] = wv.x[e];
      } else {
        const float* W = (const float*)Wv;
        float4 w0 = *(const float4*)(W + base);
        float4 w1 = *(const float4*)(W + base + 4);
        Blds[n8 + 0][kk] = f2b(w0.x); Blds[n8 + 1][kk] = f2b(w0.y);
        Blds[n8 + 2][kk] = f2b(w0.z); Blds[n8 + 3][kk] = f2b(w0.w);
        Blds[n8 + 4][kk] = f2b(w1.x); Blds[n8 + 5][kk] = f2b(w1.y);
        Blds[n8 + 6][kk] = f2b(w1.z); Blds[n8 + 7][kk] = f2b(w1.w);
      }
    }
    __syncthreads();
    bf16x8 af[4], bf_[4];
    #pragma unroll
    for (int mi = 0; mi < 4; ++mi) af[mi] = *(const bf16x8*)&Alds[wr * 64 + mi * 16 + l16][lq * 8];
    #pragma unroll
    for (int ni = 0; ni < 4; ++ni) bf_[ni] = *(const bf16x8*)&Blds[wc * 64 + ni * 16 + l16][lq * 8];
    #pragma unroll
    for (int mi = 0; mi < 4; ++mi)
      #pragma unroll
      for (int ni = 0; ni < 4; ++ni)
        acc[mi][ni] = mfma16(af[mi], bf_[ni], acc[mi][ni]);
  }
  // epilogue: C/D layout col=lane&15, row=(lane>>4)*4+j (m89)
  #pragma unroll
  for (int ni = 0; ni < 4; ++ni) {
    int col = n0 + wc * 64 + ni * 16 + l16;
    float bv = wbf ? b2f(((const unsigned short*)biasv)[col]) : ((const float*)biasv)[col];
    #pragma unroll
    for (int mi = 0; mi < 4; ++mi)
      #pragma unroll
      for (int j = 0; j < 4; ++j) {
        int row = m0 + wr * 64 + mi * 16 + lq * 4 + j;
        size_t idx = (size_t)(crow0 + row) * N + col;
        float v = acc[mi][ni][j] + bv;
        if (obf) ((unsigned short*)Cv)[idx] = f2b(v);
        else     ((float*)Cv)[idx] = v;
      }
  }
}

// ---------------- naive attention (bisection reference; batch-local pointers) ---
// 1 wave/block; thread = one q row. RoPE applied on the fly to Q and K rows.
// Qp/Kp/Vp: [S][1024] bf16 ws (pre-RoPE). dist: [S][S] int32. table follows mode.
__global__ __launch_bounds__(64) void k_attn_naive(const unsigned short* __restrict__ Qp,
                                                   const unsigned short* __restrict__ Kp,
                                                   const unsigned short* __restrict__ Vp,
                                                   const int* __restrict__ dist,
                                                   const void* __restrict__ tablev,
                                                   const float* __restrict__ tab,
                                                   unsigned short* __restrict__ AO,
                                                   const int* __restrict__ mode) {
  int md = mode[0];
  int qt = blockIdx.x & 31, h = blockIdx.x >> 5;   // grid 512 = 16 h * 32 qt
  int lane = threadIdx.x;
  int q = qt * 64 + lane;

  __shared__ float Klds[64][65];
  __shared__ float Vlds[64][65];
  __shared__ float Slds[64][65];

  float qv[64];
  {
    const unsigned short* qs = Qp + (size_t)q * DM_ + h * DH_;
    #pragma unroll
    for (int i = 0; i < 32; ++i) {
      float e = b2f(qs[2 * i]), o = b2f(qs[2 * i + 1]);
      float2 sc = *(const float2*)(tab + ((size_t)q * 32 + i) * 2);
      qv[2 * i]     = (e * sc.y - o * sc.x) * 0.125f;
      qv[2 * i + 1] = (o * sc.y + e * sc.x) * 0.125f;
    }
  }

  float oacc[64];
  #pragma unroll
  for (int d = 0; d < 64; ++d) oacc[d] = 0.f;
  float m = -1e30f, l = 0.f;

  const int* drow = dist + (size_t)q * S_;

  for (int kv = 0; kv < S_; kv += 64) {
    __syncthreads();
    {
      int s = kv + lane;
      const unsigned short* ks = Kp + (size_t)s * DM_ + h * DH_;
      #pragma unroll
      for (int i = 0; i < 32; ++i) {
        float e = b2f(ks[2 * i]), o = b2f(ks[2 * i + 1]);
        float2 sc = *(const float2*)(tab + ((size_t)s * 32 + i) * 2);
        Klds[lane][2 * i]     = e * sc.y - o * sc.x;
        Klds[lane][2 * i + 1] = o * sc.y + e * sc.x;
      }
      const unsigned short* vs = Vp + (size_t)s * DM_ + h * DH_;
      #pragma unroll
      for (int d = 0; d < 64; ++d) Vlds[lane][d] = b2f(vs[d]);
    }
    __syncthreads();

    float tm = -1e30f;
    for (int key = 0; key < 64; ++key) {
      float d0 = 0.f, d1 = 0.f, d2 = 0.f, d3 = 0.f;
      #pragma unroll
      for (int d = 0; d < 64; d += 4) {
        d0 += qv[d]     * Klds[key][d];
        d1 += qv[d + 1] * Klds[key][d + 1];
        d2 += qv[d + 2] * Klds[key][d + 2];
        d3 += qv[d + 3] * Klds[key][d + 3];
      }
      int di = drow[kv + key];
      float bv = 0.f;
      if (di >= 0) {
        int ti = (di < PV_ ? di : PV_ - 1) * H_ + h;
        bv = md ? b2f(((const unsigned short*)tablev)[ti]) : ((const float*)tablev)[ti];
      }
      float scv = (d0 + d1) + (d2 + d3) + bv;
      Slds[lane][key] = scv;
      tm = fmaxf(tm, scv);
    }
    float mn = fmaxf(m, tm);
    float scl = expf(m - mn);
    l *= scl;
    #pragma unroll
    for (int d = 0; d < 64; ++d) oacc[d] *= scl;
    m = mn;
    for (int key = 0; key < 64; ++key) {
      float p = expf(Slds[lane][key] - mn);
      l += p;
      #pragma unroll
      for (int d = 0; d < 64; ++d) oacc[d] += p * Vlds[key][d];
    }
  }

  float inv = 1.f / l;
  unsigned short* ao = AO + (size_t)q * DM_ + h * DH_;
  #pragma unroll
  for (int d = 0; d < 64; ++d) ao[d] = f2b(oacc[d] * inv);
}

// --------------------------------------------------------------------------------
extern "C" void kernel_launch(void* const* d_in, const int* in_sizes, int n_in,
                              void* d_out, int out_size, void* d_ws, size_t ws_size,
                              hipStream_t stream) {
  const void* x    = d_in[0];
  const int*  dist = (const int*)d_in[1];
  const void* Wq   = d_in[2];
  const void* bq   = d_in[3];
  const void* Wk   = d_in[4];
  const void* bk   = d_in[5];
  const void* Wv   = d_in[6];
  const void* bv   = d_in[7];
  const void* Wo   = d_in[8];
  const void* bo   = d_in[9];
  const void* tabb = d_in[10];

  // workspace (reused per batch): 0.5 + 4*4 MB + flag
  char* ws = (char*)d_ws;
  const size_t SZ_TAB = (size_t)S_ * 32 * 2 * 4;       // 512 KB
  const size_t SZ_T   = (size_t)S_ * DM_ * 2;          // 4 MB (per-batch bf16)
  float* rtab = (float*)ws;
  size_t off = SZ_TAB;
  unsigned short* Qp = (unsigned short*)(ws + off); off += SZ_T;
  unsigned short* Kp = (unsigned short*)(ws + off); off += SZ_T;
  unsigned short* Vp = (unsigned short*)(ws + off); off += SZ_T;
  unsigned short* AO = (unsigned short*)(ws + off); off += SZ_T;
  int* mode = (int*)(ws + off); off += 256;

  k_probe<<<dim3(1), dim3(256), 0, stream>>>((const unsigned short*)x, mode);
  k_ropetab<<<dim3(256), dim3(256), 0, stream>>>(rtab);

  for (int b = 0; b < B_; ++b) {
    const int* db = dist + (size_t)b * S_ * S_;

    // projections: A = x (dtype per mode), out = bf16 workspace
    k_gemmW<<<dim3(8, 16), 256, 0, stream>>>(x, Wq, bq, Qp, S_, DM_, DM_, mode, 2, 1, b * S_, 0);
    k_gemmW<<<dim3(8, 16), 256, 0, stream>>>(x, Wk, bk, Kp, S_, DM_, DM_, mode, 2, 1, b * S_, 0);
    k_gemmW<<<dim3(8, 16), 256, 0, stream>>>(x, Wv, bv, Vp, S_, DM_, DM_, mode, 2, 1, b * S_, 0);

    k_attn_naive<<<dim3(512), dim3(64), 0, stream>>>(Qp, Kp, Vp, db, tabb, rtab, AO, mode);

    // output projection: A = bf16 workspace, out dtype per mode
    k_gemmW<<<dim3(8, 16), 256, 0, stream>>>(AO, Wo, bo, d_out, S_, DM_, DM_, mode, 1, 2, 0, b * S_);
  }
}

// Round 7
// 517.585 us; speedup vs baseline: 8.7094x; 8.7094x over previous
//
#include <hip/hip_runtime.h>
#include <hip/hip_bf16.h>
#include <math.h>

#define B_   2
#define S_   2048
#define H_   16
#define DH_  64
#define DM_  1024
#define M_   (B_*S_)   // 4096
#define PV_  512

typedef __attribute__((ext_vector_type(8))) short bf16x8;
typedef __attribute__((ext_vector_type(4))) float f32x4;

__device__ __forceinline__ float b2f(unsigned short u) {
  union { unsigned int i; float f; } v; v.i = ((unsigned int)u) << 16; return v.f;
}
__device__ __forceinline__ unsigned short f2b(float f) {
  union { float f; unsigned int i; } v; v.f = f;
  return (unsigned short)((v.i + 0x7fffu + ((v.i >> 16) & 1u)) >> 16);  // RNE
}
__device__ __forceinline__ f32x4 mfma16(bf16x8 a, bf16x8 b, f32x4 c) {
  return __builtin_amdgcn_mfma_f32_16x16x32_bf16(a, b, c, 0, 0, 0);
}

// ---------------- RoPE sin/cos table: tab[s][i] = {sin, cos} (float2), i in [0,32)
__global__ void k_ropetab(float* tab) {
  int idx = blockIdx.x * 256 + threadIdx.x;       // s*32 + i
  if (idx >= S_ * 32) return;
  int s = idx >> 5, i = idx & 31;
  double inv = exp(-((double)(2 * i) / 64.0) * log(10000.0));
  double f = (double)s * inv;
  tab[idx * 2 + 0] = (float)sin(f);
  tab[idx * 2 + 1] = (float)cos(f);
}

// ---------------- GEMM: acc = A[M][K] * W[K][N] + bias[N]
// A: f32 input (AF32) or bf16 workspace. W,bias: f32. OF32: write f32 (else bf16).
// 128x128 tile, BK=32, 4 waves each 64x64 (4x4 frags of 16x16x32 MFMA).
// ROPE: epilogue -> R[b,h,s,d] bf16 (N==1024), scale folded in.
template<bool AF32, bool ROPE, bool OF32>
__global__ __launch_bounds__(256) void k_gemmW(const void* __restrict__ Av,
                                               const float* __restrict__ W,
                                               const float* __restrict__ bias,
                                               void* __restrict__ Cv,
                                               const float* __restrict__ tab,
                                               int M, int N, int K, float scale) {
  __shared__ unsigned short Alds[128][40];   // pad 32->40
  __shared__ unsigned short Blds[128][40];   // Blds[n][k] (transposed W tile)
  int lane = threadIdx.x & 63, w = threadIdx.x >> 6;
  int wr = w >> 1, wc = w & 1;
  int l16 = lane & 15, lq = lane >> 4;
  int m0 = blockIdx.y * 128, n0 = blockIdx.x * 128;
  f32x4 acc[4][4];
  #pragma unroll
  for (int a = 0; a < 4; ++a)
    #pragma unroll
    for (int b = 0; b < 4; ++b) acc[a][b] = (f32x4){0.f, 0.f, 0.f, 0.f};

  for (int k0 = 0; k0 < K; k0 += 32) {
    __syncthreads();
    // A: 128 rows x 32 k
    #pragma unroll
    for (int i = 0; i < 2; ++i) {
      int c = threadIdx.x + i * 256;
      int r = c >> 2, ch = (c & 3) * 8;
      size_t base = (size_t)(m0 + r) * K + k0 + ch;
      if (AF32) {
        const float* A = (const float*)Av;
        float4 f0 = *(const float4*)(A + base);
        float4 f1 = *(const float4*)(A + base + 4);
        unsigned short* dst = &Alds[r][ch];
        dst[0] = f2b(f0.x); dst[1] = f2b(f0.y); dst[2] = f2b(f0.z); dst[3] = f2b(f0.w);
        dst[4] = f2b(f1.x); dst[5] = f2b(f1.y); dst[6] = f2b(f1.z); dst[7] = f2b(f1.w);
      } else {
        *(uint4*)&Alds[r][ch] = *(const uint4*)((const unsigned short*)Av + base);
      }
    }
    // W (f32): 32 k-rows x 128 n, coalesced read, transposed bf16 LDS write
    #pragma unroll
    for (int i = 0; i < 2; ++i) {
      int c = threadIdx.x + i * 256;                 // 0..511
      int kk = c >> 4, n8 = (c & 15) * 8;
      size_t base = (size_t)(k0 + kk) * N + n0 + n8;
      float4 w0 = *(const float4*)(W + base);
      float4 w1 = *(const float4*)(W + base + 4);
      Blds[n8 + 0][kk] = f2b(w0.x); Blds[n8 + 1][kk] = f2b(w0.y);
      Blds[n8 + 2][kk] = f2b(w0.z); Blds[n8 + 3][kk] = f2b(w0.w);
      Blds[n8 + 4][kk] = f2b(w1.x); Blds[n8 + 5][kk] = f2b(w1.y);
      Blds[n8 + 6][kk] = f2b(w1.z); Blds[n8 + 7][kk] = f2b(w1.w);
    }
    __syncthreads();
    bf16x8 af[4], bf_[4];
    #pragma unroll
    for (int mi = 0; mi < 4; ++mi) af[mi] = *(const bf16x8*)&Alds[wr * 64 + mi * 16 + l16][lq * 8];
    #pragma unroll
    for (int ni = 0; ni < 4; ++ni) bf_[ni] = *(const bf16x8*)&Blds[wc * 64 + ni * 16 + l16][lq * 8];
    #pragma unroll
    for (int mi = 0; mi < 4; ++mi)
      #pragma unroll
      for (int ni = 0; ni < 4; ++ni)
        acc[mi][ni] = mfma16(af[mi], bf_[ni], acc[mi][ni]);
  }

  // epilogue. C/D layout: col=lane&15, row=(lane>>4)*4+j (m89)
  if (!ROPE) {
    #pragma unroll
    for (int ni = 0; ni < 4; ++ni) {
      int col = n0 + wc * 64 + ni * 16 + l16;
      float bv = bias[col];
      #pragma unroll
      for (int mi = 0; mi < 4; ++mi)
        #pragma unroll
        for (int j = 0; j < 4; ++j) {
          int row = m0 + wr * 64 + mi * 16 + lq * 4 + j;
          size_t idx = (size_t)row * N + col;
          float v = acc[mi][ni][j] + bv;
          if (OF32) ((float*)Cv)[idx] = v;
          else      ((unsigned short*)Cv)[idx] = f2b(v);
        }
    }
  } else {
    // RoPE: pairs are adjacent cols = adjacent l16 lanes; partner via shfl_xor(.,1)
    #pragma unroll
    for (int ni = 0; ni < 4; ++ni) {
      int col = n0 + wc * 64 + ni * 16 + l16;        // 0..1023 = h*64 + d
      int h = col >> 6, d = col & 63;
      float bv = bias[col];
      #pragma unroll
      for (int mi = 0; mi < 4; ++mi)
        #pragma unroll
        for (int j = 0; j < 4; ++j) {
          int row = m0 + wr * 64 + mi * 16 + lq * 4 + j;
          int s = row & (S_ - 1), b = row >> 11;
          float v = acc[mi][ni][j] + bv;
          float p = __shfl_xor(v, 1, 64);            // partner column value
          float2 sc = *(const float2*)(tab + ((size_t)s * 32 + (d >> 1)) * 2);
          float o = (d & 1) ? (v * sc.y + p * sc.x)  // odd:  o*c + e*s
                            : (v * sc.y - p * sc.x); // even: e*c - o*s
          ((unsigned short*)Cv)[(((size_t)(b * H_ + h) * S_) + s) * DH_ + d] = f2b(o * scale);
        }
    }
  }
}

// ---------------- V: [b,s,h,d] -> Vt[b,h,d,s] (bf16 workspace) ------------------
__global__ __launch_bounds__(256) void k_vtrans(const unsigned short* __restrict__ Vp,
                                                unsigned short* __restrict__ Vt) {
  int bid = blockIdx.x;                            // (b*16+h)*32 + s-tile
  int st = bid & 31; int bh = bid >> 5; int h = bh & 15; int b = bh >> 4;
  int s0 = st * 64;
  __shared__ unsigned short t[64][72];
  #pragma unroll
  for (int i = 0; i < 2; ++i) {
    int c = threadIdx.x + i * 256;                 // 64 rows x 8 chunks
    int r = c >> 3, ch = (c & 7) * 8;
    *(uint4*)&t[r][ch] = *(const uint4*)(Vp + (size_t)(b * S_ + s0 + r) * DM_ + h * DH_ + ch);
  }
  __syncthreads();
  #pragma unroll
  for (int i = 0; i < 2; ++i) {
    int c = threadIdx.x + i * 256;                 // 64 d-rows x 8 s-chunks
    int dr = c >> 3, ch = (c & 7) * 8;
    union { uint4 u; unsigned short x[8]; } tb;
    #pragma unroll
    for (int e = 0; e < 8; ++e) tb.x[e] = t[ch + e][dr];
    *(uint4*)(Vt + ((size_t)bh * DH_ + dr) * S_ + s0 + ch) = tb.u;
  }
}

// ---------------- MFMA flash attention with rel-pos bias ------------------------
// block = (b, h, 64-row q tile); 4 waves, each owns 16 q rows.
// Qr/Kr: [b,h,s,d] bf16 (Q pre-scaled by 1/8); Vt: [b,h,d,s] bf16; table f32.
__global__ __launch_bounds__(256) void k_attn(const unsigned short* __restrict__ Qr,
                                              const unsigned short* __restrict__ Kr,
                                              const unsigned short* __restrict__ Vt,
                                              const int* __restrict__ dist,
                                              const float* __restrict__ table,
                                              unsigned short* __restrict__ AO) {
  int bid = blockIdx.x;                            // (b*16+h)*32 + qt
  int qt = bid & 31; int bh = bid >> 5; int h = bh & 15; int b = bh >> 4;
  int lane = threadIdx.x & 63, w = threadIdx.x >> 6;
  int l16 = lane & 15, lq = lane >> 4;
  int q0 = qt * 64;

  __shared__ unsigned short Klds[64][72];          // [key][d]
  __shared__ unsigned short Vlds[64][72];          // [d][key]
  __shared__ unsigned short Plds[4][16][72];       // per-wave P[qrow][key]

  const unsigned short* Qbase = Qr + ((size_t)bh * S_ + q0 + w * 16 + l16) * DH_;
  bf16x8 aq0 = *(const bf16x8*)(Qbase + lq * 8);
  bf16x8 aq1 = *(const bf16x8*)(Qbase + 32 + lq * 8);

  f32x4 oacc[4];
  float m_[4], l_[4];
  #pragma unroll
  for (int j = 0; j < 4; ++j) { m_[j] = -1e30f; l_[j] = 0.f; }
  #pragma unroll
  for (int td = 0; td < 4; ++td) oacc[td] = (f32x4){0.f, 0.f, 0.f, 0.f};

  const int* drow = dist + ((size_t)b * S_ + q0 + w * 16) * S_;
  const unsigned short* Ksrc0 = Kr + (size_t)bh * S_ * DH_;
  const unsigned short* Vsrc0 = Vt + (size_t)bh * DH_ * S_;

  for (int kv = 0; kv < S_; kv += 64) {
    __syncthreads();
    {
      const unsigned short* Ksrc = Ksrc0 + (size_t)kv * DH_;
      const unsigned short* Vsrc = Vsrc0 + kv;
      #pragma unroll
      for (int i = 0; i < 2; ++i) {
        int c = threadIdx.x + i * 256;             // 64 rows x 8 chunks
        int r = c >> 3, ch = (c & 7) * 8;
        *(uint4*)&Klds[r][ch] = *(const uint4*)(Ksrc + (size_t)r * DH_ + ch);
        *(uint4*)&Vlds[r][ch] = *(const uint4*)(Vsrc + (size_t)r * S_ + ch);
      }
    }
    __syncthreads();

    f32x4 sc[4];
    #pragma unroll
    for (int t = 0; t < 4; ++t) {
      bf16x8 bk0 = *(const bf16x8*)&Klds[t * 16 + l16][lq * 8];
      bf16x8 bk1 = *(const bf16x8*)&Klds[t * 16 + l16][32 + lq * 8];
      f32x4 z = (f32x4){0.f, 0.f, 0.f, 0.f};
      z = mfma16(aq0, bk0, z);
      z = mfma16(aq1, bk1, z);
      sc[t] = z;
    }

    float p[4][4], rm[4];
    #pragma unroll
    for (int j = 0; j < 4; ++j) {
      const int* dr = drow + (size_t)(lq * 4 + j) * S_ + kv;
      float best = -1e30f;
      #pragma unroll
      for (int t = 0; t < 4; ++t) {
        int di = dr[t * 16 + l16];
        float bv = 0.f;
        if (di >= 0) bv = table[(di < PV_ ? di : PV_ - 1) * H_ + h];
        float s = sc[t][j] + bv;
        sc[t][j] = s;
        best = fmaxf(best, s);
      }
      rm[j] = best;
    }
    #pragma unroll
    for (int off = 1; off < 16; off <<= 1) {
      #pragma unroll
      for (int j = 0; j < 4; ++j) rm[j] = fmaxf(rm[j], __shfl_xor(rm[j], off, 64));
    }

    float scl[4], sums[4];
    #pragma unroll
    for (int j = 0; j < 4; ++j) {
      float mn = fmaxf(m_[j], rm[j]);
      scl[j] = expf(m_[j] - mn);
      float su = 0.f;
      #pragma unroll
      for (int t = 0; t < 4; ++t) {
        float e = expf(sc[t][j] - mn);
        p[t][j] = e;
        su += e;
      }
      sums[j] = su;
      m_[j] = mn;
    }
    #pragma unroll
    for (int off = 1; off < 16; off <<= 1) {
      #pragma unroll
      for (int j = 0; j < 4; ++j) sums[j] += __shfl_xor(sums[j], off, 64);
    }
    #pragma unroll
    for (int j = 0; j < 4; ++j) l_[j] = l_[j] * scl[j] + sums[j];
    #pragma unroll
    for (int td = 0; td < 4; ++td)
      #pragma unroll
      for (int j = 0; j < 4; ++j) oacc[td][j] *= scl[j];

    #pragma unroll
    for (int j = 0; j < 4; ++j)
      #pragma unroll
      for (int t = 0; t < 4; ++t)
        Plds[w][lq * 4 + j][t * 16 + l16] = f2b(p[t][j]);
    __syncthreads();

    bf16x8 pa0 = *(const bf16x8*)&Plds[w][l16][lq * 8];
    bf16x8 pa1 = *(const bf16x8*)&Plds[w][l16][32 + lq * 8];
    #pragma unroll
    for (int td = 0; td < 4; ++td) {
      bf16x8 v0 = *(const bf16x8*)&Vlds[td * 16 + l16][lq * 8];
      bf16x8 v1 = *(const bf16x8*)&Vlds[td * 16 + l16][32 + lq * 8];
      oacc[td] = mfma16(pa0, v0, oacc[td]);
      oacc[td] = mfma16(pa1, v1, oacc[td]);
    }
  }

  float inv[4];
  #pragma unroll
  for (int j = 0; j < 4; ++j) inv[j] = 1.f / l_[j];
  #pragma unroll
  for (int td = 0; td < 4; ++td) {
    #pragma unroll
    for (int j = 0; j < 4; ++j) {
      size_t row = (size_t)b * S_ + q0 + w * 16 + lq * 4 + j;
      AO[row * DM_ + h * DH_ + td * 16 + l16] = f2b(oacc[td][j] * inv[j]);
    }
  }
}

// --------------------------------------------------------------------------------
extern "C" void kernel_launch(void* const* d_in, const int* in_sizes, int n_in,
                              void* d_out, int out_size, void* d_ws, size_t ws_size,
                              hipStream_t stream) {
  const float* x    = (const float*)d_in[0];
  const int*   dist = (const int*)d_in[1];
  const float* Wq   = (const float*)d_in[2];
  const float* bq   = (const float*)d_in[3];
  const float* Wk   = (const float*)d_in[4];
  const float* bk   = (const float*)d_in[5];
  const float* Wv   = (const float*)d_in[6];
  const float* bv   = (const float*)d_in[7];
  const float* Wo   = (const float*)d_in[8];
  const float* bo   = (const float*)d_in[9];
  const float* tabb = (const float*)d_in[10];

  // workspace: 0.5 + 8 + 8 + 8 + 8 = 32.5 MB (confirmed available by r4/r5 bit-identity)
  char* ws = (char*)d_ws;
  const size_t SZ_TAB = (size_t)S_ * 32 * 2 * 4;       // 512 KB
  const size_t SZ_T   = (size_t)M_ * DM_ * 2;          // 8 MB
  float* rtab = (float*)ws;
  size_t off = SZ_TAB;
  unsigned short* Qr   = (unsigned short*)(ws + off); off += SZ_T;
  unsigned short* Kr   = (unsigned short*)(ws + off); off += SZ_T;
  unsigned short* Vt   = (unsigned short*)(ws + off); off += SZ_T;
  unsigned short* VpAO = (unsigned short*)(ws + off); off += SZ_T;  // Vp, then AO

  k_ropetab<<<dim3(256), dim3(256), 0, stream>>>(rtab);

  // Q/K projections with fused RoPE (Q folds 1/sqrt(64)); V plain -> VpAO
  k_gemmW<true, true, false><<<dim3(8, 32), 256, 0, stream>>>(x, Wq, bq, Qr, rtab, M_, DM_, DM_, 0.125f);
  k_gemmW<true, true, false><<<dim3(8, 32), 256, 0, stream>>>(x, Wk, bk, Kr, rtab, M_, DM_, DM_, 1.0f);
  k_gemmW<true, false, false><<<dim3(8, 32), 256, 0, stream>>>(x, Wv, bv, VpAO, rtab, M_, DM_, DM_, 1.0f);
  k_vtrans<<<dim3(1024), 256, 0, stream>>>(VpAO, Vt);

  // attention writes AO into VpAO (Vp dead after k_vtrans)
  k_attn<<<dim3(1024), 256, 0, stream>>>(Qr, Kr, Vt, dist, tabb, VpAO);

  // output projection: bf16 AO x f32 Wo -> f32 out
  k_gemmW<false, false, true><<<dim3(8, 32), 256, 0, stream>>>(VpAO, Wo, bo, d_out, rtab, M_, DM_, DM_, 1.0f);
}

// Round 8
// 356.075 us; speedup vs baseline: 12.6598x; 1.4536x over previous
//
#include <hip/hip_runtime.h>
#include <hip/hip_bf16.h>
#include <math.h>

#define B_   2
#define S_   2048
#define H_   16
#define DH_  64
#define DM_  1024
#define M_   (B_*S_)   // 4096
#define PV_  512
#define LOG2E 1.4426950408889634f

typedef __attribute__((ext_vector_type(8))) short bf16x8;
typedef __attribute__((ext_vector_type(4))) float f32x4;

__device__ __forceinline__ float b2f(unsigned short u) {
  union { unsigned int i; float f; } v; v.i = ((unsigned int)u) << 16; return v.f;
}
__device__ __forceinline__ unsigned short f2b(float f) {
  union { float f; unsigned int i; } v; v.f = f;
  return (unsigned short)((v.i + 0x7fffu + ((v.i >> 16) & 1u)) >> 16);  // RNE
}
__device__ __forceinline__ f32x4 mfma16(bf16x8 a, bf16x8 b, f32x4 c) {
  return __builtin_amdgcn_mfma_f32_16x16x32_bf16(a, b, c, 0, 0, 0);
}

// ---------------- RoPE sin/cos table: tab[s][i] = {sin, cos} (float2), i in [0,32)
__global__ void k_ropetab(float* tab) {
  int idx = blockIdx.x * 256 + threadIdx.x;       // s*32 + i
  if (idx >= S_ * 32) return;
  int s = idx >> 5, i = idx & 31;
  double inv = exp(-((double)(2 * i) / 64.0) * log(10000.0));
  double f = (double)s * inv;
  tab[idx * 2 + 0] = (float)sin(f);
  tab[idx * 2 + 1] = (float)cos(f);
}

// ---------------- one-time: Wt[n][k] = bf16(W[k][n]), 1024x1024 ------------------
__global__ __launch_bounds__(256) void k_prepw(const float* __restrict__ W,
                                               unsigned short* __restrict__ Wt) {
  int r0 = blockIdx.y * 64, c0 = blockIdx.x * 64;  // r=k, c=n
  __shared__ unsigned short t[64][65];
  #pragma unroll
  for (int p = 0; p < 16; ++p) {
    int idx = p * 256 + threadIdx.x;
    int i = idx >> 6, j = idx & 63;
    t[i][j] = f2b(W[(size_t)(r0 + i) * DM_ + c0 + j]);
  }
  __syncthreads();
  #pragma unroll
  for (int p = 0; p < 16; ++p) {
    int idx = p * 256 + threadIdx.x;
    int i = idx >> 6, j = idx & 63;
    Wt[(size_t)(c0 + i) * DM_ + r0 + j] = t[j][i];
  }
}

// ---------------- GEMM: acc = A[M][K] * W[K][N] + bias[N]
// AF32: A is f32 (else bf16 ws). WB16: W pre-transposed bf16 [N][K] (else f32 [K][N]).
// OF32: write f32. ROPE: epilogue -> [b,h,s,d] bf16, scale folded.
template<bool AF32, bool ROPE, bool OF32, bool WB16>
__global__ __launch_bounds__(256) void k_gemmW(const void* __restrict__ Av,
                                               const void* __restrict__ Wv,
                                               const float* __restrict__ bias,
                                               void* __restrict__ Cv,
                                               const float* __restrict__ tab,
                                               int M, int N, int K, float scale) {
  __shared__ unsigned short Alds[128][40];   // pad 32->40
  __shared__ unsigned short Blds[128][40];   // Blds[n][k]
  int lane = threadIdx.x & 63, w = threadIdx.x >> 6;
  int wr = w >> 1, wc = w & 1;
  int l16 = lane & 15, lq = lane >> 4;
  int m0 = blockIdx.y * 128, n0 = blockIdx.x * 128;
  f32x4 acc[4][4];
  #pragma unroll
  for (int a = 0; a < 4; ++a)
    #pragma unroll
    for (int b = 0; b < 4; ++b) acc[a][b] = (f32x4){0.f, 0.f, 0.f, 0.f};

  for (int k0 = 0; k0 < K; k0 += 32) {
    __syncthreads();
    // A: 128 rows x 32 k
    #pragma unroll
    for (int i = 0; i < 2; ++i) {
      int c = threadIdx.x + i * 256;
      int r = c >> 2, ch = (c & 3) * 8;
      size_t base = (size_t)(m0 + r) * K + k0 + ch;
      if (AF32) {
        const float* A = (const float*)Av;
        float4 f0 = *(const float4*)(A + base);
        float4 f1 = *(const float4*)(A + base + 4);
        unsigned short* dst = &Alds[r][ch];
        dst[0] = f2b(f0.x); dst[1] = f2b(f0.y); dst[2] = f2b(f0.z); dst[3] = f2b(f0.w);
        dst[4] = f2b(f1.x); dst[5] = f2b(f1.y); dst[6] = f2b(f1.z); dst[7] = f2b(f1.w);
      } else {
        *(uint4*)&Alds[r][ch] = *(const uint4*)((const unsigned short*)Av + base);
      }
    }
    // W
    if (WB16) {
      #pragma unroll
      for (int i = 0; i < 2; ++i) {
        int c = threadIdx.x + i * 256;
        int r = c >> 2, ch = (c & 3) * 8;
        *(uint4*)&Blds[r][ch] =
            *(const uint4*)((const unsigned short*)Wv + (size_t)(n0 + r) * K + k0 + ch);
      }
    } else {
      #pragma unroll
      for (int i = 0; i < 2; ++i) {
        int c = threadIdx.x + i * 256;                 // 0..511
        int kk = c >> 4, n8 = (c & 15) * 8;
        size_t base = (size_t)(k0 + kk) * N + n0 + n8;
        const float* W = (const float*)Wv;
        float4 w0 = *(const float4*)(W + base);
        float4 w1 = *(const float4*)(W + base + 4);
        Blds[n8 + 0][kk] = f2b(w0.x); Blds[n8 + 1][kk] = f2b(w0.y);
        Blds[n8 + 2][kk] = f2b(w0.z); Blds[n8 + 3][kk] = f2b(w0.w);
        Blds[n8 + 4][kk] = f2b(w1.x); Blds[n8 + 5][kk] = f2b(w1.y);
        Blds[n8 + 6][kk] = f2b(w1.z); Blds[n8 + 7][kk] = f2b(w1.w);
      }
    }
    __syncthreads();
    bf16x8 af[4], bf_[4];
    #pragma unroll
    for (int mi = 0; mi < 4; ++mi) af[mi] = *(const bf16x8*)&Alds[wr * 64 + mi * 16 + l16][lq * 8];
    #pragma unroll
    for (int ni = 0; ni < 4; ++ni) bf_[ni] = *(const bf16x8*)&Blds[wc * 64 + ni * 16 + l16][lq * 8];
    #pragma unroll
    for (int mi = 0; mi < 4; ++mi)
      #pragma unroll
      for (int ni = 0; ni < 4; ++ni)
        acc[mi][ni] = mfma16(af[mi], bf_[ni], acc[mi][ni]);
  }

  // epilogue. C/D layout: col=lane&15, row=(lane>>4)*4+j (m89)
  if (!ROPE) {
    #pragma unroll
    for (int ni = 0; ni < 4; ++ni) {
      int col = n0 + wc * 64 + ni * 16 + l16;
      float bv = bias[col];
      #pragma unroll
      for (int mi = 0; mi < 4; ++mi)
        #pragma unroll
        for (int j = 0; j < 4; ++j) {
          int row = m0 + wr * 64 + mi * 16 + lq * 4 + j;
          size_t idx = (size_t)row * N + col;
          float v = acc[mi][ni][j] + bv;
          if (OF32) ((float*)Cv)[idx] = v;
          else      ((unsigned short*)Cv)[idx] = f2b(v);
        }
    }
  } else {
    #pragma unroll
    for (int ni = 0; ni < 4; ++ni) {
      int col = n0 + wc * 64 + ni * 16 + l16;        // 0..1023 = h*64 + d
      int h = col >> 6, d = col & 63;
      float bv = bias[col];
      #pragma unroll
      for (int mi = 0; mi < 4; ++mi)
        #pragma unroll
        for (int j = 0; j < 4; ++j) {
          int row = m0 + wr * 64 + mi * 16 + lq * 4 + j;
          int s = row & (S_ - 1), b = row >> 11;
          float v = acc[mi][ni][j] + bv;
          float p = __shfl_xor(v, 1, 64);            // partner column value
          float2 sc = *(const float2*)(tab + ((size_t)s * 32 + (d >> 1)) * 2);
          float o = (d & 1) ? (v * sc.y + p * sc.x)
                            : (v * sc.y - p * sc.x);
          ((unsigned short*)Cv)[(((size_t)(b * H_ + h) * S_) + s) * DH_ + d] = f2b(o * scale);
        }
    }
  }
}

// ---------------- V: [b,s,h,d] -> Vt[b,h,d,s] (bf16 workspace) ------------------
__global__ __launch_bounds__(256) void k_vtrans(const unsigned short* __restrict__ Vp,
                                                unsigned short* __restrict__ Vt) {
  int bid = blockIdx.x;                            // (b*16+h)*32 + s-tile
  int st = bid & 31; int bh = bid >> 5; int h = bh & 15; int b = bh >> 4;
  int s0 = st * 64;
  __shared__ unsigned short t[64][72];
  #pragma unroll
  for (int i = 0; i < 2; ++i) {
    int c = threadIdx.x + i * 256;
    int r = c >> 3, ch = (c & 7) * 8;
    *(uint4*)&t[r][ch] = *(const uint4*)(Vp + (size_t)(b * S_ + s0 + r) * DM_ + h * DH_ + ch);
  }
  __syncthreads();
  #pragma unroll
  for (int i = 0; i < 2; ++i) {
    int c = threadIdx.x + i * 256;
    int dr = c >> 3, ch = (c & 7) * 8;
    union { uint4 u; unsigned short x[8]; } tb;
    #pragma unroll
    for (int e = 0; e < 8; ++e) tb.x[e] = t[ch + e][dr];
    *(uint4*)(Vt + ((size_t)bh * DH_ + dr) * S_ + s0 + ch) = tb.u;
  }
}

// ---------------- MFMA flash attention with rel-pos bias ------------------------
// block = (b, h, 64-row q tile); 4 waves, each owns 16 q rows.
__global__ __launch_bounds__(256) void k_attn(const unsigned short* __restrict__ Qr,
                                              const unsigned short* __restrict__ Kr,
                                              const unsigned short* __restrict__ Vt,
                                              const int* __restrict__ dist,
                                              const float* __restrict__ table,
                                              unsigned short* __restrict__ AO) {
  int bid = blockIdx.x;                            // (b*16+h)*32 + qt
  int qt = bid & 31; int bh = bid >> 5; int h = bh & 15; int b = bh >> 4;
  int lane = threadIdx.x & 63, w = threadIdx.x >> 6;
  int l16 = lane & 15, lq = lane >> 4;
  int q0 = qt * 64;

  __shared__ unsigned short Klds[64][72];          // [key][d]
  __shared__ unsigned short Vlds[64][72];          // [d][key]
  __shared__ unsigned short Plds[4][16][72];       // per-wave P[qrow][key]
  __shared__ float tlds[PV_];                      // this head's bias column

  for (int i = threadIdx.x; i < PV_; i += 256) tlds[i] = table[i * H_ + h];

  const unsigned short* Qbase = Qr + ((size_t)bh * S_ + q0 + w * 16 + l16) * DH_;
  bf16x8 aq0 = *(const bf16x8*)(Qbase + lq * 8);
  bf16x8 aq1 = *(const bf16x8*)(Qbase + 32 + lq * 8);

  f32x4 oacc[4];
  float m_[4], l_[4];
  #pragma unroll
  for (int j = 0; j < 4; ++j) { m_[j] = -1e30f; l_[j] = 0.f; }
  #pragma unroll
  for (int td = 0; td < 4; ++td) oacc[td] = (f32x4){0.f, 0.f, 0.f, 0.f};

  const int* drow = dist + ((size_t)b * S_ + q0 + w * 16) * S_;
  const unsigned short* Ksrc0 = Kr + (size_t)bh * S_ * DH_;
  const unsigned short* Vsrc0 = Vt + (size_t)bh * DH_ * S_;

  for (int kv = 0; kv < S_; kv += 64) {
    __syncthreads();                               // prev PV done; tlds visible after next bar
    {
      const unsigned short* Ksrc = Ksrc0 + (size_t)kv * DH_;
      const unsigned short* Vsrc = Vsrc0 + kv;
      #pragma unroll
      for (int i = 0; i < 2; ++i) {
        int c = threadIdx.x + i * 256;
        int r = c >> 3, ch = (c & 7) * 8;
        *(uint4*)&Klds[r][ch] = *(const uint4*)(Ksrc + (size_t)r * DH_ + ch);
        *(uint4*)&Vlds[r][ch] = *(const uint4*)(Vsrc + (size_t)r * S_ + ch);
      }
    }
    __syncthreads();

    // S = Q K^T (Q pre-scaled)
    f32x4 sc[4];
    #pragma unroll
    for (int t = 0; t < 4; ++t) {
      bf16x8 bk0 = *(const bf16x8*)&Klds[t * 16 + l16][lq * 8];
      bf16x8 bk1 = *(const bf16x8*)&Klds[t * 16 + l16][32 + lq * 8];
      f32x4 z = (f32x4){0.f, 0.f, 0.f, 0.f};
      z = mfma16(aq0, bk0, z);
      z = mfma16(aq1, bk1, z);
      sc[t] = z;
    }

    // + rel-pos bias from LDS; row max
    float rm[4];
    #pragma unroll
    for (int j = 0; j < 4; ++j) {
      const int* dr = drow + (size_t)(lq * 4 + j) * S_ + kv;
      float best = -1e30f;
      #pragma unroll
      for (int t = 0; t < 4; ++t) {
        int di = dr[t * 16 + l16];
        float bv = (di >= 0) ? tlds[di < PV_ ? di : PV_ - 1] : 0.f;
        float s = sc[t][j] + bv;
        sc[t][j] = s;
        best = fmaxf(best, s);
      }
      rm[j] = best;
    }
    #pragma unroll
    for (int off = 1; off < 16; off <<= 1) {
      #pragma unroll
      for (int j = 0; j < 4; ++j) rm[j] = fmaxf(rm[j], __shfl_xor(rm[j], off, 64));
    }

    // defer-max (T13): rescale only if some row grew > THR=8
    bool need = false;
    #pragma unroll
    for (int j = 0; j < 4; ++j) need = need || (rm[j] > m_[j] + 8.f);
    if (__any(need)) {
      #pragma unroll
      for (int j = 0; j < 4; ++j) {
        float mn = fmaxf(m_[j], rm[j]);
        float scl = exp2f((m_[j] - mn) * LOG2E);
        l_[j] *= scl;
        #pragma unroll
        for (int td = 0; td < 4; ++td) oacc[td][j] *= scl;
        m_[j] = mn;
      }
    }

    // p = exp(s - m), sums
    float p[4][4], sums[4];
    #pragma unroll
    for (int j = 0; j < 4; ++j) {
      float su = 0.f;
      #pragma unroll
      for (int t = 0; t < 4; ++t) {
        float e = exp2f((sc[t][j] - m_[j]) * LOG2E);
        p[t][j] = e;
        su += e;
      }
      sums[j] = su;
    }
    #pragma unroll
    for (int off = 1; off < 16; off <<= 1) {
      #pragma unroll
      for (int j = 0; j < 4; ++j) sums[j] += __shfl_xor(sums[j], off, 64);
    }
    #pragma unroll
    for (int j = 0; j < 4; ++j) l_[j] += sums[j];

    // P -> per-wave LDS (same-wave RAW; no barrier needed)
    #pragma unroll
    for (int j = 0; j < 4; ++j)
      #pragma unroll
      for (int t = 0; t < 4; ++t)
        Plds[w][lq * 4 + j][t * 16 + l16] = f2b(p[t][j]);

    bf16x8 pa0 = *(const bf16x8*)&Plds[w][l16][lq * 8];
    bf16x8 pa1 = *(const bf16x8*)&Plds[w][l16][32 + lq * 8];
    #pragma unroll
    for (int td = 0; td < 4; ++td) {
      bf16x8 v0 = *(const bf16x8*)&Vlds[td * 16 + l16][lq * 8];
      bf16x8 v1 = *(const bf16x8*)&Vlds[td * 16 + l16][32 + lq * 8];
      oacc[td] = mfma16(pa0, v0, oacc[td]);
      oacc[td] = mfma16(pa1, v1, oacc[td]);
    }
  }

  float inv[4];
  #pragma unroll
  for (int j = 0; j < 4; ++j) inv[j] = 1.f / l_[j];
  #pragma unroll
  for (int td = 0; td < 4; ++td) {
    #pragma unroll
    for (int j = 0; j < 4; ++j) {
      size_t row = (size_t)b * S_ + q0 + w * 16 + lq * 4 + j;
      AO[row * DM_ + h * DH_ + td * 16 + l16] = f2b(oacc[td][j] * inv[j]);
    }
  }
}

// --------------------------------------------------------------------------------
extern "C" void kernel_launch(void* const* d_in, const int* in_sizes, int n_in,
                              void* d_out, int out_size, void* d_ws, size_t ws_size,
                              hipStream_t stream) {
  const float* x    = (const float*)d_in[0];
  const int*   dist = (const int*)d_in[1];
  const float* Wq   = (const float*)d_in[2];
  const float* bq   = (const float*)d_in[3];
  const float* Wk   = (const float*)d_in[4];
  const float* bk   = (const float*)d_in[5];
  const float* Wv   = (const float*)d_in[6];
  const float* bv   = (const float*)d_in[7];
  const float* Wo   = (const float*)d_in[8];
  const float* bo   = (const float*)d_in[9];
  const float* tabb = (const float*)d_in[10];

  char* ws = (char*)d_ws;
  const size_t SZ_TAB = (size_t)S_ * 32 * 2 * 4;       // 512 KB
  const size_t SZ_T   = (size_t)M_ * DM_ * 2;          // 8 MB
  const size_t SZ_W   = (size_t)DM_ * DM_ * 2;         // 2 MB
  float* rtab = (float*)ws;
  size_t off = SZ_TAB;
  unsigned short* Qr   = (unsigned short*)(ws + off); off += SZ_T;
  unsigned short* Kr   = (unsigned short*)(ws + off); off += SZ_T;
  unsigned short* Vt   = (unsigned short*)(ws + off); off += SZ_T;
  unsigned short* VpAO = (unsigned short*)(ws + off); off += SZ_T;  // Vp, then AO
  unsigned short* Wtq  = (unsigned short*)(ws + off); off += SZ_W;
  unsigned short* Wtk  = (unsigned short*)(ws + off); off += SZ_W;
  unsigned short* Wtv  = (unsigned short*)(ws + off); off += SZ_W;
  unsigned short* Wto  = (unsigned short*)(ws + off); off += SZ_W;
  bool prep = ws_size >= off;                          // 40.5 MB needed for Wt path

  k_ropetab<<<dim3(256), dim3(256), 0, stream>>>(rtab);

  if (prep) {
    k_prepw<<<dim3(16, 16), 256, 0, stream>>>(Wq, Wtq);
    k_prepw<<<dim3(16, 16), 256, 0, stream>>>(Wk, Wtk);
    k_prepw<<<dim3(16, 16), 256, 0, stream>>>(Wv, Wtv);
    k_prepw<<<dim3(16, 16), 256, 0, stream>>>(Wo, Wto);
    k_gemmW<true, true, false, true><<<dim3(8, 32), 256, 0, stream>>>(x, Wtq, bq, Qr, rtab, M_, DM_, DM_, 0.125f);
    k_gemmW<true, true, false, true><<<dim3(8, 32), 256, 0, stream>>>(x, Wtk, bk, Kr, rtab, M_, DM_, DM_, 1.0f);
    k_gemmW<true, false, false, true><<<dim3(8, 32), 256, 0, stream>>>(x, Wtv, bv, VpAO, rtab, M_, DM_, DM_, 1.0f);
  } else {
    k_gemmW<true, true, false, false><<<dim3(8, 32), 256, 0, stream>>>(x, Wq, bq, Qr, rtab, M_, DM_, DM_, 0.125f);
    k_gemmW<true, true, false, false><<<dim3(8, 32), 256, 0, stream>>>(x, Wk, bk, Kr, rtab, M_, DM_, DM_, 1.0f);
    k_gemmW<true, false, false, false><<<dim3(8, 32), 256, 0, stream>>>(x, Wv, bv, VpAO, rtab, M_, DM_, DM_, 1.0f);
  }
  k_vtrans<<<dim3(1024), 256, 0, stream>>>(VpAO, Vt);

  k_attn<<<dim3(1024), 256, 0, stream>>>(Qr, Kr, Vt, dist, tabb, VpAO);

  if (prep) {
    k_gemmW<false, false, true, true><<<dim3(8, 32), 256, 0, stream>>>(VpAO, Wto, bo, d_out, rtab, M_, DM_, DM_, 1.0f);
  } else {
    k_gemmW<false, false, true, false><<<dim3(8, 32), 256, 0, stream>>>(VpAO, Wo, bo, d_out, rtab, M_, DM_, DM_, 1.0f);
  }
}

// Round 9
// 275.898 us; speedup vs baseline: 16.3387x; 1.2906x over previous
//
#include <hip/hip_runtime.h>
#include <hip/hip_bf16.h>
#include <math.h>

#define B_   2
#define S_   2048
#define H_   16
#define DH_  64
#define DM_  1024
#define M_   (B_*S_)   // 4096
#define PV_  512
#define LOG2E 1.4426950408889634f

typedef __attribute__((ext_vector_type(8))) short bf16x8;
typedef __attribute__((ext_vector_type(4))) float f32x4;

__device__ __forceinline__ float b2f(unsigned short u) {
  union { unsigned int i; float f; } v; v.i = ((unsigned int)u) << 16; return v.f;
}
__device__ __forceinline__ unsigned short f2b(float f) {
  union { float f; unsigned int i; } v; v.f = f;
  return (unsigned short)((v.i + 0x7fffu + ((v.i >> 16) & 1u)) >> 16);  // RNE
}
__device__ __forceinline__ f32x4 mfma16(bf16x8 a, bf16x8 b, f32x4 c) {
  return __builtin_amdgcn_mfma_f32_16x16x32_bf16(a, b, c, 0, 0, 0);
}

// ---------------- RoPE sin/cos table: tab[s][i] = {sin, cos} (float2), i in [0,32)
__global__ void k_ropetab(float* tab) {
  int idx = blockIdx.x * 256 + threadIdx.x;       // s*32 + i
  if (idx >= S_ * 32) return;
  int s = idx >> 5, i = idx & 31;
  double inv = exp(-((double)(2 * i) / 64.0) * log(10000.0));
  double f = (double)s * inv;
  tab[idx * 2 + 0] = (float)sin(f);
  tab[idx * 2 + 1] = (float)cos(f);
}

// ---------------- one-time: x (f32) -> xb (bf16), 4096x1024 ---------------------
__global__ __launch_bounds__(256) void k_xcast(const float* __restrict__ x,
                                               unsigned short* __restrict__ xb) {
  int idx = blockIdx.x * 256 + threadIdx.x;       // chunks of 8
  const float4 f0 = *(const float4*)(x + (size_t)idx * 8);
  const float4 f1 = *(const float4*)(x + (size_t)idx * 8 + 4);
  union { uint4 u; unsigned short s[8]; } o;
  o.s[0] = f2b(f0.x); o.s[1] = f2b(f0.y); o.s[2] = f2b(f0.z); o.s[3] = f2b(f0.w);
  o.s[4] = f2b(f1.x); o.s[5] = f2b(f1.y); o.s[6] = f2b(f1.z); o.s[7] = f2b(f1.w);
  *(uint4*)(xb + (size_t)idx * 8) = o.u;
}

// ---------------- one-time: Wt[n][k] = bf16(W[k][n]), 1024x1024 ------------------
__global__ __launch_bounds__(256) void k_prepw(const float* __restrict__ W,
                                               unsigned short* __restrict__ Wt) {
  int r0 = blockIdx.y * 64, c0 = blockIdx.x * 64;  // r=k, c=n
  __shared__ unsigned short t[64][65];
  #pragma unroll
  for (int p = 0; p < 16; ++p) {
    int idx = p * 256 + threadIdx.x;
    int i = idx >> 6, j = idx & 63;
    t[i][j] = f2b(W[(size_t)(r0 + i) * DM_ + c0 + j]);
  }
  __syncthreads();
  #pragma unroll
  for (int p = 0; p < 16; ++p) {
    int idx = p * 256 + threadIdx.x;
    int i = idx >> 6, j = idx & 63;
    Wt[(size_t)(c0 + i) * DM_ + r0 + j] = t[j][i];
  }
}

// ---------------- GEMM: acc = A[M][K] * W[K][N] + bias[N]
// AF32: A is f32 (else bf16). WB16: W pre-transposed bf16 [N][K] (else f32 [K][N]).
// OF32: write f32. ROPE: epilogue -> [b,h,s,d] bf16, scale folded.
template<bool AF32, bool ROPE, bool OF32, bool WB16>
__global__ __launch_bounds__(256) void k_gemmW(const void* __restrict__ Av,
                                               const void* __restrict__ Wv,
                                               const float* __restrict__ bias,
                                               void* __restrict__ Cv,
                                               const float* __restrict__ tab,
                                               int M, int N, int K, float scale) {
  __shared__ unsigned short Alds[128][40];   // pad 32->40
  __shared__ unsigned short Blds[128][40];   // Blds[n][k]
  int lane = threadIdx.x & 63, w = threadIdx.x >> 6;
  int wr = w >> 1, wc = w & 1;
  int l16 = lane & 15, lq = lane >> 4;
  int m0 = blockIdx.y * 128, n0 = blockIdx.x * 128;
  f32x4 acc[4][4];
  #pragma unroll
  for (int a = 0; a < 4; ++a)
    #pragma unroll
    for (int b = 0; b < 4; ++b) acc[a][b] = (f32x4){0.f, 0.f, 0.f, 0.f};

  for (int k0 = 0; k0 < K; k0 += 32) {
    __syncthreads();
    // A: 128 rows x 32 k
    #pragma unroll
    for (int i = 0; i < 2; ++i) {
      int c = threadIdx.x + i * 256;
      int r = c >> 2, ch = (c & 3) * 8;
      size_t base = (size_t)(m0 + r) * K + k0 + ch;
      if (AF32) {
        const float* A = (const float*)Av;
        float4 f0 = *(const float4*)(A + base);
        float4 f1 = *(const float4*)(A + base + 4);
        unsigned short* dst = &Alds[r][ch];
        dst[0] = f2b(f0.x); dst[1] = f2b(f0.y); dst[2] = f2b(f0.z); dst[3] = f2b(f0.w);
        dst[4] = f2b(f1.x); dst[5] = f2b(f1.y); dst[6] = f2b(f1.z); dst[7] = f2b(f1.w);
      } else {
        *(uint4*)&Alds[r][ch] = *(const uint4*)((const unsigned short*)Av + base);
      }
    }
    // W
    if (WB16) {
      #pragma unroll
      for (int i = 0; i < 2; ++i) {
        int c = threadIdx.x + i * 256;
        int r = c >> 2, ch = (c & 3) * 8;
        *(uint4*)&Blds[r][ch] =
            *(const uint4*)((const unsigned short*)Wv + (size_t)(n0 + r) * K + k0 + ch);
      }
    } else {
      #pragma unroll
      for (int i = 0; i < 2; ++i) {
        int c = threadIdx.x + i * 256;                 // 0..511
        int kk = c >> 4, n8 = (c & 15) * 8;
        size_t base = (size_t)(k0 + kk) * N + n0 + n8;
        const float* W = (const float*)Wv;
        float4 w0 = *(const float4*)(W + base);
        float4 w1 = *(const float4*)(W + base + 4);
        Blds[n8 + 0][kk] = f2b(w0.x); Blds[n8 + 1][kk] = f2b(w0.y);
        Blds[n8 + 2][kk] = f2b(w0.z); Blds[n8 + 3][kk] = f2b(w0.w);
        Blds[n8 + 4][kk] = f2b(w1.x); Blds[n8 + 5][kk] = f2b(w1.y);
        Blds[n8 + 6][kk] = f2b(w1.z); Blds[n8 + 7][kk] = f2b(w1.w);
      }
    }
    __syncthreads();
    bf16x8 af[4], bf_[4];
    #pragma unroll
    for (int mi = 0; mi < 4; ++mi) af[mi] = *(const bf16x8*)&Alds[wr * 64 + mi * 16 + l16][lq * 8];
    #pragma unroll
    for (int ni = 0; ni < 4; ++ni) bf_[ni] = *(const bf16x8*)&Blds[wc * 64 + ni * 16 + l16][lq * 8];
    #pragma unroll
    for (int mi = 0; mi < 4; ++mi)
      #pragma unroll
      for (int ni = 0; ni < 4; ++ni)
        acc[mi][ni] = mfma16(af[mi], bf_[ni], acc[mi][ni]);
  }

  // epilogue. C/D layout: col=lane&15, row=(lane>>4)*4+j (m89)
  if (!ROPE) {
    #pragma unroll
    for (int ni = 0; ni < 4; ++ni) {
      int col = n0 + wc * 64 + ni * 16 + l16;
      float bv = bias[col];
      #pragma unroll
      for (int mi = 0; mi < 4; ++mi)
        #pragma unroll
        for (int j = 0; j < 4; ++j) {
          int row = m0 + wr * 64 + mi * 16 + lq * 4 + j;
          size_t idx = (size_t)row * N + col;
          float v = acc[mi][ni][j] + bv;
          if (OF32) ((float*)Cv)[idx] = v;
          else      ((unsigned short*)Cv)[idx] = f2b(v);
        }
    }
  } else {
    #pragma unroll
    for (int ni = 0; ni < 4; ++ni) {
      int col = n0 + wc * 64 + ni * 16 + l16;        // 0..1023 = h*64 + d
      int h = col >> 6, d = col & 63;
      float bv = bias[col];
      #pragma unroll
      for (int mi = 0; mi < 4; ++mi)
        #pragma unroll
        for (int j = 0; j < 4; ++j) {
          int row = m0 + wr * 64 + mi * 16 + lq * 4 + j;
          int s = row & (S_ - 1), b = row >> 11;
          float v = acc[mi][ni][j] + bv;
          float p = __shfl_xor(v, 1, 64);            // partner column value
          float2 sc = *(const float2*)(tab + ((size_t)s * 32 + (d >> 1)) * 2);
          float o = (d & 1) ? (v * sc.y + p * sc.x)
                            : (v * sc.y - p * sc.x);
          ((unsigned short*)Cv)[(((size_t)(b * H_ + h) * S_) + s) * DH_ + d] = f2b(o * scale);
        }
    }
  }
}

// ---------------- V: [b,s,h,d] -> Vt[b,h,d,s] (bf16 workspace) ------------------
__global__ __launch_bounds__(256) void k_vtrans(const unsigned short* __restrict__ Vp,
                                                unsigned short* __restrict__ Vt) {
  int bid = blockIdx.x;                            // (b*16+h)*32 + s-tile
  int st = bid & 31; int bh = bid >> 5; int h = bh & 15; int b = bh >> 4;
  int s0 = st * 64;
  __shared__ unsigned short t[64][72];
  #pragma unroll
  for (int i = 0; i < 2; ++i) {
    int c = threadIdx.x + i * 256;
    int r = c >> 3, ch = (c & 7) * 8;
    *(uint4*)&t[r][ch] = *(const uint4*)(Vp + (size_t)(b * S_ + s0 + r) * DM_ + h * DH_ + ch);
  }
  __syncthreads();
  #pragma unroll
  for (int i = 0; i < 2; ++i) {
    int c = threadIdx.x + i * 256;
    int dr = c >> 3, ch = (c & 7) * 8;
    union { uint4 u; unsigned short x[8]; } tb;
    #pragma unroll
    for (int e = 0; e < 8; ++e) tb.x[e] = t[ch + e][dr];
    *(uint4*)(Vt + ((size_t)bh * DH_ + dr) * S_ + s0 + ch) = tb.u;
  }
}

// ---------------- MFMA flash attention with rel-pos bias ------------------------
// block = (b, h, 64-row q tile); 4 waves, each owns 16 q rows.
__global__ __launch_bounds__(256) void k_attn(const unsigned short* __restrict__ Qr,
                                              const unsigned short* __restrict__ Kr,
                                              const unsigned short* __restrict__ Vt,
                                              const int* __restrict__ dist,
                                              const float* __restrict__ table,
                                              unsigned short* __restrict__ AO) {
  int bid = blockIdx.x;                            // (b*16+h)*32 + qt
  int qt = bid & 31; int bh = bid >> 5; int h = bh & 15; int b = bh >> 4;
  int lane = threadIdx.x & 63, w = threadIdx.x >> 6;
  int l16 = lane & 15, lq = lane >> 4;
  int q0 = qt * 64;

  __shared__ unsigned short Klds[64][72];          // [key][d]
  __shared__ unsigned short Vlds[64][72];          // [d][key]
  __shared__ unsigned short Plds[4][16][72];       // per-wave P[qrow][key]
  __shared__ float tlds[PV_];                      // this head's bias column

  for (int i = threadIdx.x; i < PV_; i += 256) tlds[i] = table[i * H_ + h];

  const unsigned short* Qbase = Qr + ((size_t)bh * S_ + q0 + w * 16 + l16) * DH_;
  bf16x8 aq0 = *(const bf16x8*)(Qbase + lq * 8);
  bf16x8 aq1 = *(const bf16x8*)(Qbase + 32 + lq * 8);

  f32x4 oacc[4];
  float m_[4], l_[4];                              // l_ = PER-LANE partial sums
  #pragma unroll
  for (int j = 0; j < 4; ++j) { m_[j] = -1e30f; l_[j] = 0.f; }
  #pragma unroll
  for (int td = 0; td < 4; ++td) oacc[td] = (f32x4){0.f, 0.f, 0.f, 0.f};

  const int* drow = dist + ((size_t)b * S_ + q0 + w * 16) * S_;
  const unsigned short* Ksrc0 = Kr + (size_t)bh * S_ * DH_;
  const unsigned short* Vsrc0 = Vt + (size_t)bh * DH_ * S_;

  // dist prefetch: dc = current tile's indices, dn = next
  int dc[4][4], dn[4][4];
  #pragma unroll
  for (int j = 0; j < 4; ++j) {
    const int* dr = drow + (size_t)(lq * 4 + j) * S_;
    #pragma unroll
    for (int t = 0; t < 4; ++t) dc[j][t] = dr[t * 16 + l16];
  }

  for (int kv = 0; kv < S_; kv += 64) {
    __syncthreads();                               // prev PV done before restage
    {
      const unsigned short* Ksrc = Ksrc0 + (size_t)kv * DH_;
      const unsigned short* Vsrc = Vsrc0 + kv;
      #pragma unroll
      for (int i = 0; i < 2; ++i) {
        int c = threadIdx.x + i * 256;
        int r = c >> 3, ch = (c & 7) * 8;
        *(uint4*)&Klds[r][ch] = *(const uint4*)(Ksrc + (size_t)r * DH_ + ch);
        *(uint4*)&Vlds[r][ch] = *(const uint4*)(Vsrc + (size_t)r * S_ + ch);
      }
    }
    // prefetch next tile's dist while staging is in flight
    {
      int kvn = (kv + 64 < S_) ? kv + 64 : 0;
      #pragma unroll
      for (int j = 0; j < 4; ++j) {
        const int* dr = drow + (size_t)(lq * 4 + j) * S_ + kvn;
        #pragma unroll
        for (int t = 0; t < 4; ++t) dn[j][t] = dr[t * 16 + l16];
      }
    }
    __syncthreads();

    // S = Q K^T (Q pre-scaled)
    f32x4 sc[4];
    #pragma unroll
    for (int t = 0; t < 4; ++t) {
      bf16x8 bk0 = *(const bf16x8*)&Klds[t * 16 + l16][lq * 8];
      bf16x8 bk1 = *(const bf16x8*)&Klds[t * 16 + l16][32 + lq * 8];
      f32x4 z = (f32x4){0.f, 0.f, 0.f, 0.f};
      z = mfma16(aq0, bk0, z);
      z = mfma16(aq1, bk1, z);
      sc[t] = z;
    }

    // + rel-pos bias (LDS); per-lane row max only
    float rm[4];
    #pragma unroll
    for (int j = 0; j < 4; ++j) {
      float best = -1e30f;
      #pragma unroll
      for (int t = 0; t < 4; ++t) {
        int di = dc[j][t];
        float bv = (di >= 0) ? tlds[di < PV_ ? di : PV_ - 1] : 0.f;
        float s = sc[t][j] + bv;
        sc[t][j] = s;
        best = fmaxf(best, s);
      }
      rm[j] = best;
    }

    // defer-max (T13): rescale only if some lane's max grew past m+8
    bool need = (rm[0] > m_[0] + 8.f) || (rm[1] > m_[1] + 8.f) ||
                (rm[2] > m_[2] + 8.f) || (rm[3] > m_[3] + 8.f);
    if (__any(need)) {
      #pragma unroll
      for (int off = 1; off < 16; off <<= 1) {
        #pragma unroll
        for (int j = 0; j < 4; ++j) rm[j] = fmaxf(rm[j], __shfl_xor(rm[j], off, 64));
      }
      #pragma unroll
      for (int j = 0; j < 4; ++j) {
        float mn = fmaxf(m_[j], rm[j]);
        float scl = exp2f((m_[j] - mn) * LOG2E);
        l_[j] *= scl;
        #pragma unroll
        for (int td = 0; td < 4; ++td) oacc[td][j] *= scl;
        m_[j] = mn;
      }
    }

    // p = exp(s - m); accumulate per-lane partial l
    float p[4][4];
    #pragma unroll
    for (int j = 0; j < 4; ++j) {
      float su = 0.f;
      #pragma unroll
      for (int t = 0; t < 4; ++t) {
        float e = exp2f((sc[t][j] - m_[j]) * LOG2E);
        p[t][j] = e;
        su += e;
      }
      l_[j] += su;
    }

    // P -> per-wave LDS (same-wave RAW; no barrier needed)
    #pragma unroll
    for (int j = 0; j < 4; ++j)
      #pragma unroll
      for (int t = 0; t < 4; ++t)
        Plds[w][lq * 4 + j][t * 16 + l16] = f2b(p[t][j]);

    bf16x8 pa0 = *(const bf16x8*)&Plds[w][l16][lq * 8];
    bf16x8 pa1 = *(const bf16x8*)&Plds[w][l16][32 + lq * 8];
    #pragma unroll
    for (int td = 0; td < 4; ++td) {
      bf16x8 v0 = *(const bf16x8*)&Vlds[td * 16 + l16][lq * 8];
      bf16x8 v1 = *(const bf16x8*)&Vlds[td * 16 + l16][32 + lq * 8];
      oacc[td] = mfma16(pa0, v0, oacc[td]);
      oacc[td] = mfma16(pa1, v1, oacc[td]);
    }

    // rotate dist prefetch
    #pragma unroll
    for (int j = 0; j < 4; ++j)
      #pragma unroll
      for (int t = 0; t < 4; ++t) dc[j][t] = dn[j][t];
  }

  // final cross-lane l reduce (16 l16-lanes per row group), then normalize
  #pragma unroll
  for (int off = 1; off < 16; off <<= 1) {
    #pragma unroll
    for (int j = 0; j < 4; ++j) l_[j] += __shfl_xor(l_[j], off, 64);
  }
  float inv[4];
  #pragma unroll
  for (int j = 0; j < 4; ++j) inv[j] = 1.f / l_[j];
  #pragma unroll
  for (int td = 0; td < 4; ++td) {
    #pragma unroll
    for (int j = 0; j < 4; ++j) {
      size_t row = (size_t)b * S_ + q0 + w * 16 + lq * 4 + j;
      AO[row * DM_ + h * DH_ + td * 16 + l16] = f2b(oacc[td][j] * inv[j]);
    }
  }
}

// --------------------------------------------------------------------------------
extern "C" void kernel_launch(void* const* d_in, const int* in_sizes, int n_in,
                              void* d_out, int out_size, void* d_ws, size_t ws_size,
                              hipStream_t stream) {
  const float* x    = (const float*)d_in[0];
  const int*   dist = (const int*)d_in[1];
  const float* Wq   = (const float*)d_in[2];
  const float* bq   = (const float*)d_in[3];
  const float* Wk   = (const float*)d_in[4];
  const float* bk   = (const float*)d_in[5];
  const float* Wv   = (const float*)d_in[6];
  const float* bv   = (const float*)d_in[7];
  const float* Wo   = (const float*)d_in[8];
  const float* bo   = (const float*)d_in[9];
  const float* tabb = (const float*)d_in[10];

  char* ws = (char*)d_ws;
  const size_t SZ_TAB = (size_t)S_ * 32 * 2 * 4;       // 512 KB
  const size_t SZ_T   = (size_t)M_ * DM_ * 2;          // 8 MB
  const size_t SZ_W   = (size_t)DM_ * DM_ * 2;         // 2 MB
  float* rtab = (float*)ws;
  size_t off = SZ_TAB;
  unsigned short* Qr   = (unsigned short*)(ws + off); off += SZ_T;
  unsigned short* Kr   = (unsigned short*)(ws + off); off += SZ_T;
  unsigned short* Vt   = (unsigned short*)(ws + off); off += SZ_T;
  unsigned short* VpAO = (unsigned short*)(ws + off); off += SZ_T;  // Vp, then AO
  unsigned short* Wtq  = (unsigned short*)(ws + off); off += SZ_W;
  unsigned short* Wtk  = (unsigned short*)(ws + off); off += SZ_W;
  unsigned short* Wtv  = (unsigned short*)(ws + off); off += SZ_W;
  unsigned short* Wto  = (unsigned short*)(ws + off); off += SZ_W;
  size_t off_prep = off;
  unsigned short* xb   = (unsigned short*)(ws + off); off += SZ_T;
  bool prep  = ws_size >= off_prep;                    // 40.5 MB: Wt path
  bool xcast = ws_size >= off;                         // 48.5 MB: + bf16 x

  k_ropetab<<<dim3(256), dim3(256), 0, stream>>>(rtab);

  if (prep) {
    k_prepw<<<dim3(16, 16), 256, 0, stream>>>(Wq, Wtq);
    k_prepw<<<dim3(16, 16), 256, 0, stream>>>(Wk, Wtk);
    k_prepw<<<dim3(16, 16), 256, 0, stream>>>(Wv, Wtv);
    k_prepw<<<dim3(16, 16), 256, 0, stream>>>(Wo, Wto);
    if (xcast) {
      k_xcast<<<dim3(M_ * DM_ / 8 / 256), 256, 0, stream>>>(x, xb);
      k_gemmW<false, true, false, true><<<dim3(8, 32), 256, 0, stream>>>(xb, Wtq, bq, Qr, rtab, M_, DM_, DM_, 0.125f);
      k_gemmW<false, true, false, true><<<dim3(8, 32), 256, 0, stream>>>(xb, Wtk, bk, Kr, rtab, M_, DM_, DM_, 1.0f);
      k_gemmW<false, false, false, true><<<dim3(8, 32), 256, 0, stream>>>(xb, Wtv, bv, VpAO, rtab, M_, DM_, DM_, 1.0f);
    } else {
      k_gemmW<true, true, false, true><<<dim3(8, 32), 256, 0, stream>>>(x, Wtq, bq, Qr, rtab, M_, DM_, DM_, 0.125f);
      k_gemmW<true, true, false, true><<<dim3(8, 32), 256, 0, stream>>>(x, Wtk, bk, Kr, rtab, M_, DM_, DM_, 1.0f);
      k_gemmW<true, false, false, true><<<dim3(8, 32), 256, 0, stream>>>(x, Wtv, bv, VpAO, rtab, M_, DM_, DM_, 1.0f);
    }
  } else {
    k_gemmW<true, true, false, false><<<dim3(8, 32), 256, 0, stream>>>(x, Wq, bq, Qr, rtab, M_, DM_, DM_, 0.125f);
    k_gemmW<true, true, false, false><<<dim3(8, 32), 256, 0, stream>>>(x, Wk, bk, Kr, rtab, M_, DM_, DM_, 1.0f);
    k_gemmW<true, false, false, false><<<dim3(8, 32), 256, 0, stream>>>(x, Wv, bv, VpAO, rtab, M_, DM_, DM_, 1.0f);
  }
  k_vtrans<<<dim3(1024), 256, 0, stream>>>(VpAO, Vt);

  k_attn<<<dim3(1024), 256, 0, stream>>>(Qr, Kr, Vt, dist, tabb, VpAO);

  if (prep) {
    k_gemmW<false, false, true, true><<<dim3(8, 32), 256, 0, stream>>>(VpAO, Wto, bo, d_out, rtab, M_, DM_, DM_, 1.0f);
  } else {
    k_gemmW<false, false, true, false><<<dim3(8, 32), 256, 0, stream>>>(VpAO, Wo, bo, d_out, rtab, M_, DM_, DM_, 1.0f);
  }
}